// Round 18
// baseline (156.556 us; speedup 1.0000x reference)
//
#include <hip/hip_runtime.h>
#include <hip/hip_bf16.h>

typedef __bf16 bf16_t;
typedef __bf16 bf16x4 __attribute__((ext_vector_type(4)));
typedef __bf16 bf16x8 __attribute__((ext_vector_type(8)));
typedef float f32x4 __attribute__((ext_vector_type(4)));
typedef float f32x16 __attribute__((ext_vector_type(16)));
typedef unsigned int u32x4 __attribute__((ext_vector_type(4)));

#define HEADS 12
#define DHEAD 64
#define NSEQ 2048
#define BATCH 4
#define DMODEL 768
#define NINNER 768

// q pre-scale: (1/sqrt(64)) * log2(e), so attn uses raw v_exp_f32 (2^x), no prescale
#define QSCALE 0.18033688011112042f

// ---- async global->LDS, 16B per lane; LDS dest = wave-uniform base + lane*16 ----
__device__ __forceinline__ void gl_lds16(const bf16_t* g, bf16_t* l) {
  __builtin_amdgcn_global_load_lds(
      (const __attribute__((address_space(1))) void*)g,
      (__attribute__((address_space(3))) void*)l, 16, 0, 0);
}

// pack two floats to bf16 pair, elem a in LOW 16 bits (compiler RNE casts — verified R5)
__device__ __forceinline__ unsigned pack_bf16_2(float a, float b) {
  unsigned lo = (unsigned)__builtin_bit_cast(unsigned short, (bf16_t)a);
  unsigned hi = (unsigned)__builtin_bit_cast(unsigned short, (bf16_t)b);
  return lo | (hi << 16);
}

// ---------------- fused prologue: cast x -> bf16, transpose+cast both weights -------
// blocks [0,384): cast 8192x768 f32->bf16 (grid-stride)
// blocks [384,2112): Wqkv [768][2304] -> wqkvT [2304][768] bf16  (72x24 tiles)
// blocks [2112,2688): Wout [768][768] -> woutT [768][768] bf16   (24x24 tiles)
__global__ void prologue_kernel(const float* __restrict__ x,
                                const float* __restrict__ Wqkv,
                                const float* __restrict__ Wout,
                                bf16_t* __restrict__ xb,
                                bf16_t* __restrict__ wqkvT,
                                bf16_t* __restrict__ woutT) {
  __shared__ float tile[32][33];
  const int bid = blockIdx.x;
  const int tid = threadIdx.x;
  if (bid < 384) {
    const int n8 = (8192 * 768) / 8;
    int i = bid * 256 + tid;
    const int stride = 384 * 256;
    for (; i < n8; i += stride) {
      const f32x4* p = (const f32x4*)(x + (size_t)i * 8);
      f32x4 a = p[0], b = p[1];
      bf16x8 o;
#pragma unroll
      for (int j = 0; j < 4; ++j) { o[j] = (bf16_t)a[j]; o[j + 4] = (bf16_t)b[j]; }
      *(bf16x8*)(xb + (size_t)i * 8) = o;
    }
  } else {
    const float* in;
    bf16_t* out;
    int K, N, bx, by;
    if (bid < 2112) {
      const int tt = bid - 384;
      in = Wqkv; out = wqkvT; K = 768; N = 2304;
      bx = (tt % 72) * 32; by = (tt / 72) * 32;
    } else {
      const int tt = bid - 2112;
      in = Wout; out = woutT; K = 768; N = 768;
      bx = (tt % 24) * 32; by = (tt / 24) * 32;
    }
    const int tx = tid & 31, ty = tid >> 5;
#pragma unroll
    for (int i = ty; i < 32; i += 8)
      tile[i][tx] = in[(size_t)(by + i) * N + bx + tx];
    __syncthreads();
#pragma unroll
    for (int i = ty; i < 32; i += 8)
      out[(size_t)(bx + i) * K + by + tx] = (bf16_t)tile[tx][i];
  }
}

// ---------------- bf16 GEMM: C[M,N] = A[M,K] @ Bt[N,K]^T ----------------
// R18: BM=64 for BOTH gemms (path correctness+perf verified by gemm2 in R17).
// gemm1: grid 128x18 = 2304 blocks = exactly 3 dispatch rounds at 3 blocks/CU
// (was 1152 @ 2/CU = 2.25 ragged rounds, 16 waves/CU). 24KB LDS, 8 indep acc
// chains, 2D grid — all prior failure modes (R12 occupancy/locality, R14 ILP)
// held fixed. Sync: R16 pipelined BK=32 skeleton (race-screened drain form, R10).
// MODE 0: q/k scatter into [B,H,N,64] (q scaled by QSCALE); V written TRANSPOSED
//         [B,H,64,N] with packed bf16x4 stores. MODE 1: fp32 out + bias.
template <int MODE, int BM>
__global__ __launch_bounds__(256, (BM == 64) ? 3 : 2)
void gemm_bt(const bf16_t* __restrict__ A, const bf16_t* __restrict__ Bt,
             bf16_t* __restrict__ qw, bf16_t* __restrict__ kw, bf16_t* __restrict__ vtw,
             const float* __restrict__ bias, float* __restrict__ outf,
             int M, int Nn, int K) {
  constexpr int MI = BM / 32;           // acc rows per wave: 4 (BM=128) or 2 (BM=64)
  __shared__ bf16_t As[2][BM * 32];     // row-major [BM][32]
  __shared__ bf16_t Bs[2][128 * 32];
  const int tid = threadIdx.x;
  const int wid = tid >> 6;
  const int lane = tid & 63;
  const int m0 = blockIdx.x * BM;
  const int n0 = blockIdx.y * 128;
  const int wm = (wid >> 1) * (BM / 2);
  const int wn = (wid & 1) * 64;
  const int fr = lane & 15;
  const int fg = lane >> 4;
  const int srow = lane >> 2;        // 0..15 row within 16-row chunk
  const int scol = (lane & 3) * 8;   // k-col (8 bf16 = 16B)

  f32x4 acc[MI][4] = {};

  const int NT = K >> 5;  // 32-wide K-steps (24 for K=768)
  auto stageG = [&](int bsel, int t) {
    const int kt = t * 32;
#pragma unroll
    for (int i = 0; i < BM / 64; ++i) {            // A: BM/16 chunks, BM/64 per wave
      const int c = wid * (BM / 64) + i;
      gl_lds16(A + (size_t)(m0 + c * 16 + srow) * K + kt + scol, &As[bsel][c * 512]);
    }
#pragma unroll
    for (int i = 0; i < 2; ++i) {                  // B: 8 chunks, 2 per wave
      const int c = wid * 2 + i;
      gl_lds16(Bt + (size_t)(n0 + c * 16 + srow) * K + kt + scol, &Bs[bsel][c * 512]);
    }
  };

  stageG(0, 0);

  for (int t = 0; t < NT; ++t) {
    const int buf = t & 1;
    // explicit drain of tile t's staging before the barrier (race-screened, R10)
    asm volatile("s_waitcnt vmcnt(0) lgkmcnt(0)" ::: "memory");
    __builtin_amdgcn_sched_barrier(0);
    __syncthreads();
    if (t + 1 < NT) stageG(buf ^ 1, t + 1);  // in flight across this step's compute

    bf16x8 af[MI], bfr[4];
#pragma unroll
    for (int mi = 0; mi < MI; ++mi)
      af[mi] = *(const bf16x8*)(&As[buf][(wm + mi * 16 + fr) * 32 + fg * 8]);
#pragma unroll
    for (int ni = 0; ni < 4; ++ni)
      bfr[ni] = *(const bf16x8*)(&Bs[buf][(wn + ni * 16 + fr) * 32 + fg * 8]);
#pragma unroll
    for (int mi = 0; mi < MI; ++mi)
#pragma unroll
      for (int ni = 0; ni < 4; ++ni)
        acc[mi][ni] = __builtin_amdgcn_mfma_f32_16x16x32_bf16(af[mi], bfr[ni], acc[mi][ni], 0, 0, 0);
  }

  // epilogue: C/D layout col = lane&15, row = (lane>>4)*4 + r
  if (MODE == 0 && n0 >= 2 * NINNER) {
    // V block: write transposed, packed. rows n..n+3 are consecutive -> bf16x4 at [d][n].
#pragma unroll
    for (int mi = 0; mi < MI; ++mi) {
#pragma unroll
      for (int ni = 0; ni < 4; ++ni) {
        const int col = n0 + wn + ni * 16 + fr - 2 * NINNER;  // h*64 + d
        const int h = col >> 6, d = col & 63;
        const int row0 = m0 + wm + mi * 16 + fg * 4;
        const int b = row0 >> 11, n = row0 & 2047;
        bf16x4 pk;
#pragma unroll
        for (int r = 0; r < 4; ++r) pk[r] = (bf16_t)acc[mi][ni][r];
        *(bf16x4*)(vtw + ((size_t)((b * HEADS + h) * DHEAD + d)) * NSEQ + n) = pk;
      }
    }
  } else {
#pragma unroll
    for (int mi = 0; mi < MI; ++mi) {
#pragma unroll
      for (int ni = 0; ni < 4; ++ni) {
#pragma unroll
        for (int r = 0; r < 4; ++r) {
          const int row = m0 + wm + mi * 16 + fg * 4 + r;
          const int col = n0 + wn + ni * 16 + fr;
          float val = acc[mi][ni][r];
          if (MODE == 0) {
            const int which = col / NINNER;  // 0=q 1=k (v handled above)
            const int cin = col - which * NINNER;
            const int h = cin >> 6, d = cin & 63;
            const int b = row >> 11, n = row & 2047;
            bf16_t* dst = (which == 0) ? qw : kw;
            if (which == 0) val *= QSCALE;  // fold attn scale + log2(e) into q
            dst[(((size_t)(b * HEADS + h)) * NSEQ + n) * DHEAD + d] = (bf16_t)val;
          } else {
            outf[(size_t)row * Nn + col] = val + bias[col];
          }
        }
      }
    }
  }
}

// ---------------- flash attention, in-register softmax, zero-exchange ----------------
// FROZEN at R11 verified state (deterministic pass, absmax 1.95e-3, 73.6us).
// 768 blocks (XCD-swizzled), 3/CU, 4 waves x 32 q-rows, 32x32x16 MFMA, KVBLK=64.
// Swapped QK^T + sigma-permuted K staging -> PV A-frags are straight packs (no
// cross-lane exchange); row-sum via mfma(pa, ones); explicit pre-barrier vmcnt drain
// (R10 race fix — the t+1 prefetch's only drain point).
__global__ __launch_bounds__(256, 3)
void attn_fwd(const bf16_t* __restrict__ qg, const bf16_t* __restrict__ kg,
              const bf16_t* __restrict__ vtg, bf16_t* __restrict__ og) {
  __shared__ bf16_t KV[2][16 * 512];  // 16 chunks x 1KB per buffer (K: 0..7, V: 8..15)
  const int tid = threadIdx.x, wid = tid >> 6, lane = tid & 63;
  const int logical = (blockIdx.x & 7) * 96 + (blockIdx.x >> 3);
  const int bh = logical >> 4;                 // b*12 + h
  const int qbase = (logical & 15) * 128 + wid * 32;
  const bf16_t* Q = qg + (size_t)bh * NSEQ * DHEAD;
  const bf16_t* K = kg + (size_t)bh * NSEQ * DHEAD;
  const bf16_t* Vt = vtg + (size_t)bh * NSEQ * DHEAD;  // [64 d][2048 n]
  const int l31 = lane & 31, hi = lane >> 5;
  // sigma: swap bits 2 and 3 of the 5-bit row index (involution)
  const int sw = (l31 & 19) | ((l31 & 4) << 1) | ((l31 & 8) >> 1);

  bf16x8 qf[4];
#pragma unroll
  for (int ks = 0; ks < 4; ++ks)
    qf[ks] = *(const bf16x8*)(Q + (size_t)(qbase + l31) * DHEAD + ks * 16 + hi * 8);

  bf16x8 onesf;
#pragma unroll
  for (int e = 0; e < 8; ++e) onesf[e] = (bf16_t)1.0f;

  f32x16 oacc[2] = {};
  f32x16 lacc = {};

  auto stage = [&](int bsel, int t) {
    const int kv0 = t * 64;
#pragma unroll
    for (int i = 0; i < 4; ++i) {
      const int c = wid * 4 + i;
      bf16_t* dst = &KV[bsel][c * 512];
      if (c < 8) {
        gl_lds16(K + (size_t)(kv0 + (c >> 2) * 32 + sw) * DHEAD + (c & 3) * 16 + hi * 8, dst);
      } else {
        gl_lds16(Vt + (size_t)(((c >> 2) & 1) * 32 + l31) * NSEQ + kv0 + (c & 3) * 16 + hi * 8, dst);
      }
    }
  };

  stage(0, 0);

  for (int t = 0; t < NSEQ / 64; ++t) {
    const int buf = t & 1;
    asm volatile("s_waitcnt vmcnt(0) lgkmcnt(0)" ::: "memory");
    __builtin_amdgcn_sched_barrier(0);
    __syncthreads();  // tile t staged & visible in KV[buf]; buf^1 free to overwrite
    if (t + 1 < NSEQ / 64) stage(buf ^ 1, t + 1);

    const bf16_t* base = &KV[buf][0];

    // --- S^T = K @ Q^T (scale + log2e pre-folded into q; K rows sigma-permuted) ---
    f32x16 sacc[2] = {};
    __builtin_amdgcn_s_setprio(1);
#pragma unroll
    for (int mi = 0; mi < 2; ++mi)
#pragma unroll
      for (int ks = 0; ks < 4; ++ks) {
        bf16x8 kf = *(const bf16x8*)(base + (mi * 4 + ks) * 512 + lane * 8);
        sacc[mi] = __builtin_amdgcn_mfma_f32_32x32x16_bf16(kf, qf[ks], sacc[mi], 0, 0, 0);
      }
    __builtin_amdgcn_s_setprio(0);

    // --- in-register softmax: P = 2^S; pa = straight packs (sigma staging) ---
    bf16x8 pa[4];
#pragma unroll
    for (int mi = 0; mi < 2; ++mi) {
      float p[16];
#pragma unroll
      for (int r = 0; r < 16; ++r) p[r] = __builtin_amdgcn_exp2f(sacc[mi][r]);
#pragma unroll
      for (int s = 0; s < 2; ++s) {
        u32x4 pw;
#pragma unroll
        for (int w = 0; w < 4; ++w)
          pw[w] = pack_bf16_2(p[8 * s + 2 * w], p[8 * s + 2 * w + 1]);
        pa[mi * 2 + s] = __builtin_bit_cast(bf16x8, pw);
      }
    }

    // --- O += P @ V ; lacc += P @ ones (row sums, same C-layout as O) ---
    __builtin_amdgcn_s_setprio(1);
#pragma unroll
    for (int ni = 0; ni < 2; ++ni)
#pragma unroll
      for (int ks = 0; ks < 4; ++ks) {
        bf16x8 vf = *(const bf16x8*)(base + (8 + ni * 4 + ks) * 512 + lane * 8);
        oacc[ni] = __builtin_amdgcn_mfma_f32_32x32x16_bf16(pa[ks], vf, oacc[ni], 0, 0, 0);
      }
#pragma unroll
    for (int ks = 0; ks < 4; ++ks)
      lacc = __builtin_amdgcn_mfma_f32_32x32x16_bf16(pa[ks], onesf, lacc, 0, 0, 0);
    __builtin_amdgcn_s_setprio(0);
  }

  // --- epilogue: lacc[r] is the softmax denominator for this reg's q-row ---
  const int b = bh / HEADS, h = bh % HEADS;
#pragma unroll
  for (int r = 0; r < 16; ++r) {
    const int qq = (r & 3) + 8 * (r >> 2) + 4 * hi;   // output q-row for this reg
    const float invr = 1.0f / lacc[r];
    const int n = qbase + qq;
#pragma unroll
    for (int ni = 0; ni < 2; ++ni)
      og[((size_t)b * NSEQ + n) * DMODEL + h * DHEAD + ni * 32 + l31] =
          (bf16_t)(oacc[ni][r] * invr);
  }
}

extern "C" void kernel_launch(void* const* d_in, const int* in_sizes, int n_in,
                              void* d_out, int out_size, void* d_ws, size_t ws_size,
                              hipStream_t stream) {
  const float* x    = (const float*)d_in[0];
  const float* Wqkv = (const float*)d_in[1];
  const float* Wout = (const float*)d_in[2];
  const float* bout = (const float*)d_in[3];
  float* out = (float*)d_out;

  char* ws = (char*)d_ws;
  bf16_t* xb    = (bf16_t*)(ws + 0);          // 8192x768   bf16 = 12.58MB
  bf16_t* wqkvT = (bf16_t*)(ws + 12582912);   // 2304x768   bf16 =  3.54MB
  bf16_t* woutT = (bf16_t*)(ws + 16121856);   // 768x768    bf16 =  1.18MB
  bf16_t* qw    = (bf16_t*)(ws + 17301504);   // [B,H,N,64] bf16 = 12.58MB
  bf16_t* kw    = (bf16_t*)(ws + 29884416);
  bf16_t* vtw   = (bf16_t*)(ws + 42467328);   // [B,H,64,N] bf16 = 12.58MB (transposed)
  bf16_t* attno = (bf16_t*)(ws + 55050240);   // [B,N,768]  bf16 = 12.58MB

  prologue_kernel<<<2688, 256, 0, stream>>>(x, Wqkv, Wout, xb, wqkvT, woutT);

  gemm_bt<0, 64><<<dim3(128, 18), 256, 0, stream>>>(xb, wqkvT, qw, kw, vtw, nullptr, nullptr,
                                                    8192, 2304, 768);
  attn_fwd<<<768, 256, 0, stream>>>(qw, kw, vtw, attno);
  gemm_bt<1, 64><<<dim3(128, 6), 256, 0, stream>>>(attno, woutT, nullptr, nullptr, nullptr, bout, out,
                                                   8192, 768, 768);
}

// Round 19
// 150.591 us; speedup vs baseline: 1.0396x; 1.0396x over previous
//
#include <hip/hip_runtime.h>
#include <hip/hip_bf16.h>

typedef __bf16 bf16_t;
typedef __bf16 bf16x4 __attribute__((ext_vector_type(4)));
typedef __bf16 bf16x8 __attribute__((ext_vector_type(8)));
typedef float f32x4 __attribute__((ext_vector_type(4)));
typedef float f32x16 __attribute__((ext_vector_type(16)));
typedef unsigned int u32x4 __attribute__((ext_vector_type(4)));

#define HEADS 12
#define DHEAD 64
#define NSEQ 2048
#define BATCH 4
#define DMODEL 768
#define NINNER 768

// q pre-scale: (1/sqrt(64)) * log2(e), so attn uses raw v_exp_f32 (2^x), no prescale
#define QSCALE 0.18033688011112042f

// ---- async global->LDS, 16B per lane; LDS dest = wave-uniform base + lane*16 ----
__device__ __forceinline__ void gl_lds16(const bf16_t* g, bf16_t* l) {
  __builtin_amdgcn_global_load_lds(
      (const __attribute__((address_space(1))) void*)g,
      (__attribute__((address_space(3))) void*)l, 16, 0, 0);
}

// pack two floats to bf16 pair, elem a in LOW 16 bits (compiler RNE casts — verified R5)
__device__ __forceinline__ unsigned pack_bf16_2(float a, float b) {
  unsigned lo = (unsigned)__builtin_bit_cast(unsigned short, (bf16_t)a);
  unsigned hi = (unsigned)__builtin_bit_cast(unsigned short, (bf16_t)b);
  return lo | (hi << 16);
}

// ---------------- fused prologue: cast x -> bf16, transpose+cast both weights -------
// blocks [0,384): cast 8192x768 f32->bf16 (grid-stride)
// blocks [384,2112): Wqkv [768][2304] -> wqkvT [2304][768] bf16  (72x24 tiles)
// blocks [2112,2688): Wout [768][768] -> woutT [768][768] bf16   (24x24 tiles)
__global__ void prologue_kernel(const float* __restrict__ x,
                                const float* __restrict__ Wqkv,
                                const float* __restrict__ Wout,
                                bf16_t* __restrict__ xb,
                                bf16_t* __restrict__ wqkvT,
                                bf16_t* __restrict__ woutT) {
  __shared__ float tile[32][33];
  const int bid = blockIdx.x;
  const int tid = threadIdx.x;
  if (bid < 384) {
    const int n8 = (8192 * 768) / 8;
    int i = bid * 256 + tid;
    const int stride = 384 * 256;
    for (; i < n8; i += stride) {
      const f32x4* p = (const f32x4*)(x + (size_t)i * 8);
      f32x4 a = p[0], b = p[1];
      bf16x8 o;
#pragma unroll
      for (int j = 0; j < 4; ++j) { o[j] = (bf16_t)a[j]; o[j + 4] = (bf16_t)b[j]; }
      *(bf16x8*)(xb + (size_t)i * 8) = o;
    }
  } else {
    const float* in;
    bf16_t* out;
    int K, N, bx, by;
    if (bid < 2112) {
      const int tt = bid - 384;
      in = Wqkv; out = wqkvT; K = 768; N = 2304;
      bx = (tt % 72) * 32; by = (tt / 72) * 32;
    } else {
      const int tt = bid - 2112;
      in = Wout; out = woutT; K = 768; N = 768;
      bx = (tt % 24) * 32; by = (tt / 24) * 32;
    }
    const int tx = tid & 31, ty = tid >> 5;
#pragma unroll
    for (int i = ty; i < 32; i += 8)
      tile[i][tx] = in[(size_t)(by + i) * N + bx + tx];
    __syncthreads();
#pragma unroll
    for (int i = ty; i < 32; i += 8)
      out[(size_t)(bx + i) * K + by + tx] = (bf16_t)tile[tx][i];
  }
}

// ---------------- bf16 GEMM: C[M,N] = A[M,K] @ Bt[N,K]^T ----------------
// R19 = exact revert to R17 (measured best: 150.96us). Templated BM:
// gemm1 BM=128 (dim3(64,18)): R18's BM=64 port regressed (+5.5us — doubled B-panel
//   re-reads outweighed the occupancy gain; 2.25 rounds were already well-packed).
// gemm2 BM=64 (dim3(128,6) = 768 blocks = exactly 3/CU): verified win in R17 —
//   kills the 1.5-blocks/CU imbalance of the 384-block grid. 8 indep acc chains.
// Sync: R16 pipelined BK=32 skeleton (attn's race-screened drain->barrier->issue).
// MODE 0: q/k scatter into [B,H,N,64] (q scaled by QSCALE); V written TRANSPOSED
//         [B,H,64,N] with packed bf16x4 stores. MODE 1: fp32 out + bias.
template <int MODE, int BM>
__global__ __launch_bounds__(256, (BM == 64) ? 3 : 2)
void gemm_bt(const bf16_t* __restrict__ A, const bf16_t* __restrict__ Bt,
             bf16_t* __restrict__ qw, bf16_t* __restrict__ kw, bf16_t* __restrict__ vtw,
             const float* __restrict__ bias, float* __restrict__ outf,
             int M, int Nn, int K) {
  constexpr int MI = BM / 32;           // acc rows per wave: 4 (BM=128) or 2 (BM=64)
  __shared__ bf16_t As[2][BM * 32];     // row-major [BM][32]
  __shared__ bf16_t Bs[2][128 * 32];
  const int tid = threadIdx.x;
  const int wid = tid >> 6;
  const int lane = tid & 63;
  const int m0 = blockIdx.x * BM;
  const int n0 = blockIdx.y * 128;
  const int wm = (wid >> 1) * (BM / 2);
  const int wn = (wid & 1) * 64;
  const int fr = lane & 15;
  const int fg = lane >> 4;
  const int srow = lane >> 2;        // 0..15 row within 16-row chunk
  const int scol = (lane & 3) * 8;   // k-col (8 bf16 = 16B)

  f32x4 acc[MI][4] = {};

  const int NT = K >> 5;  // 32-wide K-steps (24 for K=768)
  auto stageG = [&](int bsel, int t) {
    const int kt = t * 32;
#pragma unroll
    for (int i = 0; i < BM / 64; ++i) {            // A: BM/16 chunks, BM/64 per wave
      const int c = wid * (BM / 64) + i;
      gl_lds16(A + (size_t)(m0 + c * 16 + srow) * K + kt + scol, &As[bsel][c * 512]);
    }
#pragma unroll
    for (int i = 0; i < 2; ++i) {                  // B: 8 chunks, 2 per wave
      const int c = wid * 2 + i;
      gl_lds16(Bt + (size_t)(n0 + c * 16 + srow) * K + kt + scol, &Bs[bsel][c * 512]);
    }
  };

  stageG(0, 0);

  for (int t = 0; t < NT; ++t) {
    const int buf = t & 1;
    // explicit drain of tile t's staging before the barrier (race-screened, R10)
    asm volatile("s_waitcnt vmcnt(0) lgkmcnt(0)" ::: "memory");
    __builtin_amdgcn_sched_barrier(0);
    __syncthreads();
    if (t + 1 < NT) stageG(buf ^ 1, t + 1);  // in flight across this step's compute

    bf16x8 af[MI], bfr[4];
#pragma unroll
    for (int mi = 0; mi < MI; ++mi)
      af[mi] = *(const bf16x8*)(&As[buf][(wm + mi * 16 + fr) * 32 + fg * 8]);
#pragma unroll
    for (int ni = 0; ni < 4; ++ni)
      bfr[ni] = *(const bf16x8*)(&Bs[buf][(wn + ni * 16 + fr) * 32 + fg * 8]);
#pragma unroll
    for (int mi = 0; mi < MI; ++mi)
#pragma unroll
      for (int ni = 0; ni < 4; ++ni)
        acc[mi][ni] = __builtin_amdgcn_mfma_f32_16x16x32_bf16(af[mi], bfr[ni], acc[mi][ni], 0, 0, 0);
  }

  // epilogue: C/D layout col = lane&15, row = (lane>>4)*4 + r
  if (MODE == 0 && n0 >= 2 * NINNER) {
    // V block: write transposed, packed. rows n..n+3 are consecutive -> bf16x4 at [d][n].
#pragma unroll
    for (int mi = 0; mi < MI; ++mi) {
#pragma unroll
      for (int ni = 0; ni < 4; ++ni) {
        const int col = n0 + wn + ni * 16 + fr - 2 * NINNER;  // h*64 + d
        const int h = col >> 6, d = col & 63;
        const int row0 = m0 + wm + mi * 16 + fg * 4;
        const int b = row0 >> 11, n = row0 & 2047;
        bf16x4 pk;
#pragma unroll
        for (int r = 0; r < 4; ++r) pk[r] = (bf16_t)acc[mi][ni][r];
        *(bf16x4*)(vtw + ((size_t)((b * HEADS + h) * DHEAD + d)) * NSEQ + n) = pk;
      }
    }
  } else {
#pragma unroll
    for (int mi = 0; mi < MI; ++mi) {
#pragma unroll
      for (int ni = 0; ni < 4; ++ni) {
#pragma unroll
        for (int r = 0; r < 4; ++r) {
          const int row = m0 + wm + mi * 16 + fg * 4 + r;
          const int col = n0 + wn + ni * 16 + fr;
          float val = acc[mi][ni][r];
          if (MODE == 0) {
            const int which = col / NINNER;  // 0=q 1=k (v handled above)
            const int cin = col - which * NINNER;
            const int h = cin >> 6, d = cin & 63;
            const int b = row >> 11, n = row & 2047;
            bf16_t* dst = (which == 0) ? qw : kw;
            if (which == 0) val *= QSCALE;  // fold attn scale + log2(e) into q
            dst[(((size_t)(b * HEADS + h)) * NSEQ + n) * DHEAD + d] = (bf16_t)val;
          } else {
            outf[(size_t)row * Nn + col] = val + bias[col];
          }
        }
      }
    }
  }
}

// ---------------- flash attention, in-register softmax, zero-exchange ----------------
// FROZEN at R11 verified state (deterministic pass, absmax 1.95e-3, 73.6us).
// 768 blocks (XCD-swizzled), 3/CU, 4 waves x 32 q-rows, 32x32x16 MFMA, KVBLK=64.
// Swapped QK^T + sigma-permuted K staging -> PV A-frags are straight packs (no
// cross-lane exchange); row-sum via mfma(pa, ones); explicit pre-barrier vmcnt drain
// (R10 race fix — the t+1 prefetch's only drain point).
__global__ __launch_bounds__(256, 3)
void attn_fwd(const bf16_t* __restrict__ qg, const bf16_t* __restrict__ kg,
              const bf16_t* __restrict__ vtg, bf16_t* __restrict__ og) {
  __shared__ bf16_t KV[2][16 * 512];  // 16 chunks x 1KB per buffer (K: 0..7, V: 8..15)
  const int tid = threadIdx.x, wid = tid >> 6, lane = tid & 63;
  const int logical = (blockIdx.x & 7) * 96 + (blockIdx.x >> 3);
  const int bh = logical >> 4;                 // b*12 + h
  const int qbase = (logical & 15) * 128 + wid * 32;
  const bf16_t* Q = qg + (size_t)bh * NSEQ * DHEAD;
  const bf16_t* K = kg + (size_t)bh * NSEQ * DHEAD;
  const bf16_t* Vt = vtg + (size_t)bh * NSEQ * DHEAD;  // [64 d][2048 n]
  const int l31 = lane & 31, hi = lane >> 5;
  // sigma: swap bits 2 and 3 of the 5-bit row index (involution)
  const int sw = (l31 & 19) | ((l31 & 4) << 1) | ((l31 & 8) >> 1);

  bf16x8 qf[4];
#pragma unroll
  for (int ks = 0; ks < 4; ++ks)
    qf[ks] = *(const bf16x8*)(Q + (size_t)(qbase + l31) * DHEAD + ks * 16 + hi * 8);

  bf16x8 onesf;
#pragma unroll
  for (int e = 0; e < 8; ++e) onesf[e] = (bf16_t)1.0f;

  f32x16 oacc[2] = {};
  f32x16 lacc = {};

  auto stage = [&](int bsel, int t) {
    const int kv0 = t * 64;
#pragma unroll
    for (int i = 0; i < 4; ++i) {
      const int c = wid * 4 + i;
      bf16_t* dst = &KV[bsel][c * 512];
      if (c < 8) {
        gl_lds16(K + (size_t)(kv0 + (c >> 2) * 32 + sw) * DHEAD + (c & 3) * 16 + hi * 8, dst);
      } else {
        gl_lds16(Vt + (size_t)(((c >> 2) & 1) * 32 + l31) * NSEQ + kv0 + (c & 3) * 16 + hi * 8, dst);
      }
    }
  };

  stage(0, 0);

  for (int t = 0; t < NSEQ / 64; ++t) {
    const int buf = t & 1;
    asm volatile("s_waitcnt vmcnt(0) lgkmcnt(0)" ::: "memory");
    __builtin_amdgcn_sched_barrier(0);
    __syncthreads();  // tile t staged & visible in KV[buf]; buf^1 free to overwrite
    if (t + 1 < NSEQ / 64) stage(buf ^ 1, t + 1);

    const bf16_t* base = &KV[buf][0];

    // --- S^T = K @ Q^T (scale + log2e pre-folded into q; K rows sigma-permuted) ---
    f32x16 sacc[2] = {};
    __builtin_amdgcn_s_setprio(1);
#pragma unroll
    for (int mi = 0; mi < 2; ++mi)
#pragma unroll
      for (int ks = 0; ks < 4; ++ks) {
        bf16x8 kf = *(const bf16x8*)(base + (mi * 4 + ks) * 512 + lane * 8);
        sacc[mi] = __builtin_amdgcn_mfma_f32_32x32x16_bf16(kf, qf[ks], sacc[mi], 0, 0, 0);
      }
    __builtin_amdgcn_s_setprio(0);

    // --- in-register softmax: P = 2^S; pa = straight packs (sigma staging) ---
    bf16x8 pa[4];
#pragma unroll
    for (int mi = 0; mi < 2; ++mi) {
      float p[16];
#pragma unroll
      for (int r = 0; r < 16; ++r) p[r] = __builtin_amdgcn_exp2f(sacc[mi][r]);
#pragma unroll
      for (int s = 0; s < 2; ++s) {
        u32x4 pw;
#pragma unroll
        for (int w = 0; w < 4; ++w)
          pw[w] = pack_bf16_2(p[8 * s + 2 * w], p[8 * s + 2 * w + 1]);
        pa[mi * 2 + s] = __builtin_bit_cast(bf16x8, pw);
      }
    }

    // --- O += P @ V ; lacc += P @ ones (row sums, same C-layout as O) ---
    __builtin_amdgcn_s_setprio(1);
#pragma unroll
    for (int ni = 0; ni < 2; ++ni)
#pragma unroll
      for (int ks = 0; ks < 4; ++ks) {
        bf16x8 vf = *(const bf16x8*)(base + (8 + ni * 4 + ks) * 512 + lane * 8);
        oacc[ni] = __builtin_amdgcn_mfma_f32_32x32x16_bf16(pa[ks], vf, oacc[ni], 0, 0, 0);
      }
#pragma unroll
    for (int ks = 0; ks < 4; ++ks)
      lacc = __builtin_amdgcn_mfma_f32_32x32x16_bf16(pa[ks], onesf, lacc, 0, 0, 0);
    __builtin_amdgcn_s_setprio(0);
  }

  // --- epilogue: lacc[r] is the softmax denominator for this reg's q-row ---
  const int b = bh / HEADS, h = bh % HEADS;
#pragma unroll
  for (int r = 0; r < 16; ++r) {
    const int qq = (r & 3) + 8 * (r >> 2) + 4 * hi;   // output q-row for this reg
    const float invr = 1.0f / lacc[r];
    const int n = qbase + qq;
#pragma unroll
    for (int ni = 0; ni < 2; ++ni)
      og[((size_t)b * NSEQ + n) * DMODEL + h * DHEAD + ni * 32 + l31] =
          (bf16_t)(oacc[ni][r] * invr);
  }
}

extern "C" void kernel_launch(void* const* d_in, const int* in_sizes, int n_in,
                              void* d_out, int out_size, void* d_ws, size_t ws_size,
                              hipStream_t stream) {
  const float* x    = (const float*)d_in[0];
  const float* Wqkv = (const float*)d_in[1];
  const float* Wout = (const float*)d_in[2];
  const float* bout = (const float*)d_in[3];
  float* out = (float*)d_out;

  char* ws = (char*)d_ws;
  bf16_t* xb    = (bf16_t*)(ws + 0);          // 8192x768   bf16 = 12.58MB
  bf16_t* wqkvT = (bf16_t*)(ws + 12582912);   // 2304x768   bf16 =  3.54MB
  bf16_t* woutT = (bf16_t*)(ws + 16121856);   // 768x768    bf16 =  1.18MB
  bf16_t* qw    = (bf16_t*)(ws + 17301504);   // [B,H,N,64] bf16 = 12.58MB
  bf16_t* kw    = (bf16_t*)(ws + 29884416);
  bf16_t* vtw   = (bf16_t*)(ws + 42467328);   // [B,H,64,N] bf16 = 12.58MB (transposed)
  bf16_t* attno = (bf16_t*)(ws + 55050240);   // [B,N,768]  bf16 = 12.58MB

  prologue_kernel<<<2688, 256, 0, stream>>>(x, Wqkv, Wout, xb, wqkvT, woutT);

  gemm_bt<0, 128><<<dim3(64, 18), 256, 0, stream>>>(xb, wqkvT, qw, kw, vtw, nullptr, nullptr,
                                                    8192, 2304, 768);
  attn_fwd<<<768, 256, 0, stream>>>(qw, kw, vtw, attno);
  gemm_bt<1, 64><<<dim3(128, 6), 256, 0, stream>>>(attno, woutT, nullptr, nullptr, nullptr, bout, out,
                                                   8192, 768, 768);
}